// Round 1
// baseline (82.864 us; speedup 1.0000x reference)
//
#include <hip/hip_runtime.h>

// Problem constants (match reference)
constexpr int cB = 8;
constexpr int cN = 4096;
constexpr int cD = 1024;   // IN_FEATURES
constexpr int cH = 1792;   // HIDDEN_DIM

constexpr int NSPLIT = 128;   // k1 partial split over N (rows per block = 32)
constexpr int HSPLIT = 16;    // k3 partial split over H (h per block = 112)

// Workspace layout (in floats)
constexpr size_t OFF_XSUM  = 0;                               // B*D   = 8192
constexpr size_t OFF_KSUM  = OFF_XSUM + (size_t)cB * cD;      // B*H   = 14336
constexpr size_t OFF_V     = OFF_KSUM + (size_t)cB * cH;      // B*D   = 8192
constexpr size_t OFF_C     = OFF_V    + (size_t)cB * cD;      // 8 (pad 32)
constexpr size_t OFF_PART  = OFF_C + 32;                      // B*NSPLIT*D = 1,048,576
constexpr size_t OFF_VPART = OFF_PART + (size_t)cB * NSPLIT * cD; // HSPLIT*B*D = 131,072
constexpr size_t TOTAL_DET_FLOATS = OFF_VPART + (size_t)HSPLIT * cB * cD;
constexpr size_t SMALL_FLOATS     = OFF_PART;   // accumulator region for atomic fallback

// ---------------------------------------------------------------------------
// k1a: partial[b*NSPLIT+ns][d] = sum over 32 consecutive rows of x[b]
__global__ __launch_bounds__(256) void k1a_partial(const float* __restrict__ x,
                                                   float* __restrict__ part) {
    int bid = blockIdx.x;                 // 0 .. B*NSPLIT-1
    int b = bid / NSPLIT, ns = bid % NSPLIT;
    const int rows = cN / NSPLIT;         // 32
    const float4* xp = (const float4*)(x + ((size_t)b * cN + (size_t)ns * rows) * cD);
    int t = threadIdx.x;                  // 0..255 -> one float4 of the row
    float4 acc = make_float4(0.f, 0.f, 0.f, 0.f);
    for (int r = 0; r < rows; ++r) {
        float4 v = xp[(size_t)r * (cD / 4) + t];
        acc.x += v.x; acc.y += v.y; acc.z += v.z; acc.w += v.w;
    }
    ((float4*)part)[(size_t)bid * (cD / 4) + t] = acc;
}

// k1b: xsum[b][d] = sum_ns part[b*NSPLIT+ns][d]
__global__ __launch_bounds__(256) void k1b_reduce(const float* __restrict__ part,
                                                  float* __restrict__ xsum) {
    int idx = blockIdx.x * blockDim.x + threadIdx.x;  // b*cD + d, total 8192
    int b = idx / cD, d = idx % cD;
    float acc = 0.f;
    const float* p = part + (size_t)b * NSPLIT * cD + d;
    for (int ns = 0; ns < NSPLIT; ++ns) acc += p[(size_t)ns * cD];
    xsum[idx] = acc;
}

// k1 fallback: atomic accumulate directly into xsum (pre-zeroed)
__global__ __launch_bounds__(256) void k1_atomic(const float* __restrict__ x,
                                                 float* __restrict__ xsum) {
    int bid = blockIdx.x;
    int b = bid / NSPLIT, ns = bid % NSPLIT;
    const int rows = cN / NSPLIT;
    const float4* xp = (const float4*)(x + ((size_t)b * cN + (size_t)ns * rows) * cD);
    int t = threadIdx.x;
    float4 acc = make_float4(0.f, 0.f, 0.f, 0.f);
    for (int r = 0; r < rows; ++r) {
        float4 v = xp[(size_t)r * (cD / 4) + t];
        acc.x += v.x; acc.y += v.y; acc.z += v.z; acc.w += v.w;
    }
    float* dst = xsum + (size_t)b * cD + t * 4;
    atomicAdd(dst + 0, acc.x);
    atomicAdd(dst + 1, acc.y);
    atomicAdd(dst + 2, acc.z);
    atomicAdd(dst + 3, acc.w);
}

// ---------------------------------------------------------------------------
// k2: ksum[b][h] = xsum[b]·Wk[h] + N*bk[h].  One wave per h, 4 waves per block.
__global__ __launch_bounds__(256) void k2_ksum(const float* __restrict__ xsum,
                                               const float* __restrict__ Wk,
                                               const float* __restrict__ bk,
                                               float* __restrict__ ksum) {
    int bid = blockIdx.x;                      // 0 .. B*(H/4)-1
    int b = bid / (cH / 4), hblk = bid % (cH / 4);
    int wave = threadIdx.x >> 6, lane = threadIdx.x & 63;
    int h = hblk * 4 + wave;
    const float4* xs = (const float4*)(xsum + (size_t)b * cD);
    const float4* wk = (const float4*)(Wk + (size_t)h * cD);
    float acc = 0.f;
#pragma unroll
    for (int i = 0; i < 4; ++i) {
        float4 a = xs[i * 64 + lane];
        float4 w = wk[i * 64 + lane];
        acc += a.x * w.x + a.y * w.y + a.z * w.z + a.w * w.w;
    }
#pragma unroll
    for (int off = 32; off; off >>= 1) acc += __shfl_xor(acc, off);
    if (lane == 0) ksum[(size_t)b * cH + h] = acc + (float)cN * bk[h];
}

// k2b: c[b] = bq · ksum[b].  One wave per b.
__global__ void k2b_c(const float* __restrict__ bq,
                      const float* __restrict__ ksum,
                      float* __restrict__ cvec) {
    int b = blockIdx.x;
    int lane = threadIdx.x;  // block of 64
    float acc = 0.f;
    for (int h = lane; h < cH; h += 64) acc += bq[h] * ksum[(size_t)b * cH + h];
#pragma unroll
    for (int off = 32; off; off >>= 1) acc += __shfl_xor(acc, off);
    if (lane == 0) cvec[b] = acc;
}

// ---------------------------------------------------------------------------
// k3a: vpart[hs][b][d] = sum over h-chunk of Wq[h][d] * ksum[b][h]
__global__ __launch_bounds__(256) void k3a_vpart(const float* __restrict__ Wq,
                                                 const float* __restrict__ ksum,
                                                 float* __restrict__ vpart) {
    int dblk = blockIdx.x % (cD / 256);
    int hs = blockIdx.x / (cD / 256);
    int d = dblk * 256 + threadIdx.x;
    const int hper = cH / HSPLIT;  // 112
    int h0 = hs * hper;
    float acc[cB];
#pragma unroll
    for (int b = 0; b < cB; ++b) acc[b] = 0.f;
    for (int hh = 0; hh < hper; ++hh) {
        int h = h0 + hh;
        float w = Wq[(size_t)h * cD + d];
#pragma unroll
        for (int b = 0; b < cB; ++b) acc[b] += w * ksum[(size_t)b * cH + h];
    }
#pragma unroll
    for (int b = 0; b < cB; ++b)
        vpart[((size_t)hs * cB + b) * cD + d] = acc[b];
}

// k3b: v[b][d] = sum_hs vpart[hs][b][d]
__global__ __launch_bounds__(256) void k3b_vreduce(const float* __restrict__ vpart,
                                                   float* __restrict__ v) {
    int idx = blockIdx.x * blockDim.x + threadIdx.x;  // b*cD + d
    float acc = 0.f;
    for (int hs = 0; hs < HSPLIT; ++hs) acc += vpart[(size_t)hs * cB * cD + idx];
    v[idx] = acc;
}

// k3 fallback: atomic accumulate into v (pre-zeroed)
__global__ __launch_bounds__(256) void k3_atomic(const float* __restrict__ Wq,
                                                 const float* __restrict__ ksum,
                                                 float* __restrict__ v) {
    int dblk = blockIdx.x % (cD / 256);
    int hs = blockIdx.x / (cD / 256);
    int d = dblk * 256 + threadIdx.x;
    const int hper = cH / HSPLIT;
    int h0 = hs * hper;
    float acc[cB];
#pragma unroll
    for (int b = 0; b < cB; ++b) acc[b] = 0.f;
    for (int hh = 0; hh < hper; ++hh) {
        int h = h0 + hh;
        float w = Wq[(size_t)h * cD + d];
#pragma unroll
        for (int b = 0; b < cB; ++b) acc[b] += w * ksum[(size_t)b * cH + h];
    }
#pragma unroll
    for (int b = 0; b < cB; ++b) atomicAdd(&v[(size_t)b * cD + d], acc[b]);
}

// ---------------------------------------------------------------------------
// k4: scores[b][n] = (x[b,n]·v[b] + c[b]) * (1/(N*sqrt(H)))
__global__ __launch_bounds__(256) void k4_scores(const float* __restrict__ x,
                                                 const float* __restrict__ v,
                                                 const float* __restrict__ cvec,
                                                 float* __restrict__ out) {
    int row0 = blockIdx.x * 4;            // 4 rows (waves) per block, same b
    int b = row0 / cN;
    __shared__ float4 vs[cD / 4];
    int t = threadIdx.x;
    vs[t] = ((const float4*)(v + (size_t)b * cD))[t];
    __syncthreads();
    int wave = t >> 6, lane = t & 63;
    int row = row0 + wave;
    const float4* xp = (const float4*)(x + (size_t)row * cD);
    float acc = 0.f;
#pragma unroll
    for (int i = 0; i < 4; ++i) {
        float4 a = xp[i * 64 + lane];
        float4 w = vs[i * 64 + lane];
        acc += a.x * w.x + a.y * w.y + a.z * w.z + a.w * w.w;
    }
#pragma unroll
    for (int off = 32; off; off >>= 1) acc += __shfl_xor(acc, off);
    // matches reference: attn scaled by 1/sqrt(H), then mean over N keys
    const float scale = (1.0f / 4096.0f) * (1.0f / sqrtf(1792.0f));
    if (lane == 0) out[row] = (acc + cvec[b]) * scale;
}

// ---------------------------------------------------------------------------
extern "C" void kernel_launch(void* const* d_in, const int* in_sizes, int n_in,
                              void* d_out, int out_size, void* d_ws, size_t ws_size,
                              hipStream_t stream) {
    const float* x  = (const float*)d_in[0];
    const float* Wq = (const float*)d_in[1];
    const float* bq = (const float*)d_in[2];
    const float* Wk = (const float*)d_in[3];
    const float* bk = (const float*)d_in[4];
    float* out = (float*)d_out;
    float* ws  = (float*)d_ws;

    float* xsum  = ws + OFF_XSUM;
    float* ksum  = ws + OFF_KSUM;
    float* v     = ws + OFF_V;
    float* cvec  = ws + OFF_C;
    float* part  = ws + OFF_PART;
    float* vpart = ws + OFF_VPART;

    const bool det = ws_size >= TOTAL_DET_FLOATS * sizeof(float);

    // Stage 1: xsum[b][d] = sum_n x[b][n][d]   (reads x once: 128 MiB)
    if (det) {
        k1a_partial<<<cB * NSPLIT, 256, 0, stream>>>(x, part);
        k1b_reduce<<<(cB * cD) / 256, 256, 0, stream>>>(part, xsum);
    } else {
        hipMemsetAsync(d_ws, 0, SMALL_FLOATS * sizeof(float), stream);
        k1_atomic<<<cB * NSPLIT, 256, 0, stream>>>(x, xsum);
    }

    // Stage 2: ksum[b][h] = xsum[b]·Wk[h] + N*bk[h]   (reads Wk once: 7 MiB)
    k2_ksum<<<cB * (cH / 4), 256, 0, stream>>>(xsum, Wk, bk, ksum);

    // Stage 2b: c[b] = bq·ksum[b]
    k2b_c<<<cB, 64, 0, stream>>>(bq, ksum, cvec);

    // Stage 3: v[b][d] = sum_h Wq[h][d]*ksum[b][h]   (reads Wq once: 7 MiB)
    if (det) {
        k3a_vpart<<<HSPLIT * (cD / 256), 256, 0, stream>>>(Wq, ksum, vpart);
        k3b_vreduce<<<(cB * cD) / 256, 256, 0, stream>>>(vpart, v);
    } else {
        k3_atomic<<<HSPLIT * (cD / 256), 256, 0, stream>>>(Wq, ksum, v);
    }

    // Stage 4: scores = (x·v + c) * scale   (reads x again: 128 MiB, mostly L3)
    k4_scores<<<(cB * cN) / 4, 256, 0, stream>>>(x, v, cvec, out);
}

// Round 2
// 78.394 us; speedup vs baseline: 1.0570x; 1.0570x over previous
//
#include <hip/hip_runtime.h>

// Problem constants (match reference)
constexpr int cB = 8;
constexpr int cN = 4096;
constexpr int cD = 1024;   // IN_FEATURES
constexpr int cH = 1792;   // HIDDEN_DIM

constexpr int NSPLIT = 128;  // k1 partial split over N (rows per block = 32)
constexpr int CH     = 16;   // k23: h-values per block
constexpr int HS     = cH / CH;  // 112 blocks

// Workspace layout (in floats)
constexpr size_t OFF_XSUM  = 0;                                   // 8192
constexpr size_t OFF_V     = OFF_XSUM + (size_t)cB * cD;          // 8192
constexpr size_t OFF_C     = OFF_V + (size_t)cB * cD;             // 8 (pad 64)
constexpr size_t OFF_CPART = OFF_C + 64;                          // HS*B = 896 (pad 1024)
constexpr size_t OFF_VPART = OFF_CPART + 1024;                    // HS*B*D = 917504
constexpr size_t OFF_PART  = OFF_VPART + (size_t)HS * cB * cD;    // B*NSPLIT*D = 1048576
constexpr size_t TOTAL_DET_FLOATS = OFF_PART + (size_t)cB * NSPLIT * cD;
constexpr size_t SMALL_FLOATS     = OFF_CPART;  // atomic-fallback accumulator region

__device__ __forceinline__ float dot4(float4 a, float4 b) {
    return a.x * b.x + a.y * b.y + a.z * b.z + a.w * b.w;
}

// ---------------------------------------------------------------------------
// k1a: part[b*NSPLIT+ns][d] = sum over 32 consecutive rows of x[b]
__global__ __launch_bounds__(256) void k1a_partial(const float* __restrict__ x,
                                                   float* __restrict__ part) {
    int bid = blockIdx.x;                 // 0 .. B*NSPLIT-1
    int b = bid / NSPLIT, ns = bid % NSPLIT;
    const int rows = cN / NSPLIT;         // 32
    const float4* xp = (const float4*)(x + ((size_t)b * cN + (size_t)ns * rows) * cD);
    int t = threadIdx.x;                  // one float4 column of the row
    float4 acc = make_float4(0.f, 0.f, 0.f, 0.f);
    for (int r = 0; r < rows; ++r) {
        float4 v = xp[(size_t)r * (cD / 4) + t];
        acc.x += v.x; acc.y += v.y; acc.z += v.z; acc.w += v.w;
    }
    ((float4*)part)[(size_t)bid * (cD / 4) + t] = acc;
}

// k1b: xsum[b][d] = sum_ns part[b*NSPLIT+ns][d]
__global__ __launch_bounds__(256) void k1b_reduce(const float* __restrict__ part,
                                                  float* __restrict__ xsum) {
    int idx = blockIdx.x * blockDim.x + threadIdx.x;  // b*cD + d, total 8192
    int b = idx / cD, d = idx % cD;
    float acc = 0.f;
    const float* p = part + (size_t)b * NSPLIT * cD + d;
    for (int ns = 0; ns < NSPLIT; ++ns) acc += p[(size_t)ns * cD];
    xsum[idx] = acc;
}

// k1 fallback: atomic accumulate directly into xsum (pre-zeroed)
__global__ __launch_bounds__(256) void k1_atomic(const float* __restrict__ x,
                                                 float* __restrict__ xsum) {
    int bid = blockIdx.x;
    int b = bid / NSPLIT, ns = bid % NSPLIT;
    const int rows = cN / NSPLIT;
    const float4* xp = (const float4*)(x + ((size_t)b * cN + (size_t)ns * rows) * cD);
    int t = threadIdx.x;
    float4 acc = make_float4(0.f, 0.f, 0.f, 0.f);
    for (int r = 0; r < rows; ++r) {
        float4 v = xp[(size_t)r * (cD / 4) + t];
        acc.x += v.x; acc.y += v.y; acc.z += v.z; acc.w += v.w;
    }
    float* dst = xsum + (size_t)b * cD + t * 4;
    atomicAdd(dst + 0, acc.x);
    atomicAdd(dst + 1, acc.y);
    atomicAdd(dst + 2, acc.z);
    atomicAdd(dst + 3, acc.w);
}

// ---------------------------------------------------------------------------
// k23: fused ksum -> (vpart, cpart).  Grid = HS blocks x 512 threads.
// Wave w handles batch b=w; block handles h in [blockIdx*CH, +CH).
// ksum[b,h] = xsum[b]·Wk[h] + N*bk[h]   (wave shuffle-reduce, broadcast)
// vpart[hs][b][d] += Wq[h][d]*ksum ; cpart[hs][b] += bq[h]*ksum
__global__ __launch_bounds__(512) void k23_fused(const float* __restrict__ xsum,
                                                 const float* __restrict__ Wk,
                                                 const float* __restrict__ bk,
                                                 const float* __restrict__ Wq,
                                                 const float* __restrict__ bq,
                                                 float* __restrict__ vpart,
                                                 float* __restrict__ cpart) {
    int w = threadIdx.x >> 6, l = threadIdx.x & 63;
    int b = w;                       // 8 waves == 8 batches
    int h0 = blockIdx.x * CH;

    const float4* xs4 = (const float4*)(xsum + (size_t)b * cD);
    float4 xr[4];
#pragma unroll
    for (int j = 0; j < 4; ++j) xr[j] = xs4[l + 64 * j];

    float4 vacc[4];
#pragma unroll
    for (int j = 0; j < 4; ++j) vacc[j] = make_float4(0.f, 0.f, 0.f, 0.f);
    float cacc = 0.f;

    for (int i = 0; i < CH; ++i) {
        int h = h0 + i;
        const float4* wk4 = (const float4*)(Wk + (size_t)h * cD);
        float pd = 0.f;
#pragma unroll
        for (int j = 0; j < 4; ++j) pd += dot4(wk4[l + 64 * j], xr[j]);
#pragma unroll
        for (int off = 32; off; off >>= 1) pd += __shfl_xor(pd, off);
        float ks = pd + (float)cN * bk[h];     // ksum[b,h], all lanes hold it
        cacc += bq[h] * ks;
        const float4* wq4 = (const float4*)(Wq + (size_t)h * cD);
#pragma unroll
        for (int j = 0; j < 4; ++j) {
            float4 q = wq4[l + 64 * j];
            vacc[j].x = fmaf(q.x, ks, vacc[j].x);
            vacc[j].y = fmaf(q.y, ks, vacc[j].y);
            vacc[j].z = fmaf(q.z, ks, vacc[j].z);
            vacc[j].w = fmaf(q.w, ks, vacc[j].w);
        }
    }

    float4* vp = (float4*)(vpart + ((size_t)blockIdx.x * cB + b) * cD);
#pragma unroll
    for (int j = 0; j < 4; ++j) vp[l + 64 * j] = vacc[j];
    if (l == 0) cpart[blockIdx.x * cB + b] = cacc;
}

// k23 fallback: atomics into v, cvec (pre-zeroed)
__global__ __launch_bounds__(512) void k23_atomic(const float* __restrict__ xsum,
                                                  const float* __restrict__ Wk,
                                                  const float* __restrict__ bk,
                                                  const float* __restrict__ Wq,
                                                  const float* __restrict__ bq,
                                                  float* __restrict__ v,
                                                  float* __restrict__ cvec) {
    int w = threadIdx.x >> 6, l = threadIdx.x & 63;
    int b = w;
    int h0 = blockIdx.x * CH;
    const float4* xs4 = (const float4*)(xsum + (size_t)b * cD);
    float4 xr[4];
#pragma unroll
    for (int j = 0; j < 4; ++j) xr[j] = xs4[l + 64 * j];
    float4 vacc[4];
#pragma unroll
    for (int j = 0; j < 4; ++j) vacc[j] = make_float4(0.f, 0.f, 0.f, 0.f);
    float cacc = 0.f;
    for (int i = 0; i < CH; ++i) {
        int h = h0 + i;
        const float4* wk4 = (const float4*)(Wk + (size_t)h * cD);
        float pd = 0.f;
#pragma unroll
        for (int j = 0; j < 4; ++j) pd += dot4(wk4[l + 64 * j], xr[j]);
#pragma unroll
        for (int off = 32; off; off >>= 1) pd += __shfl_xor(pd, off);
        float ks = pd + (float)cN * bk[h];
        cacc += bq[h] * ks;
        const float4* wq4 = (const float4*)(Wq + (size_t)h * cD);
#pragma unroll
        for (int j = 0; j < 4; ++j) {
            float4 q = wq4[l + 64 * j];
            vacc[j].x = fmaf(q.x, ks, vacc[j].x);
            vacc[j].y = fmaf(q.y, ks, vacc[j].y);
            vacc[j].z = fmaf(q.z, ks, vacc[j].z);
            vacc[j].w = fmaf(q.w, ks, vacc[j].w);
        }
    }
    float* vb = v + (size_t)b * cD;
#pragma unroll
    for (int j = 0; j < 4; ++j) {
        int d = 4 * (l + 64 * j);
        atomicAdd(vb + d + 0, vacc[j].x);
        atomicAdd(vb + d + 1, vacc[j].y);
        atomicAdd(vb + d + 2, vacc[j].z);
        atomicAdd(vb + d + 3, vacc[j].w);
    }
    if (l == 0) atomicAdd(&cvec[b], cacc);
}

// kred: v[b][d] = sum_hs vpart[hs][b][d];  c[b] = sum_hs cpart[hs][b]
__global__ __launch_bounds__(256) void kred(const float* __restrict__ vpart,
                                            const float* __restrict__ cpart,
                                            float* __restrict__ v,
                                            float* __restrict__ cvec) {
    int idx = blockIdx.x * blockDim.x + threadIdx.x;  // b*cD + d, total 8192
    float acc = 0.f;
    for (int hs = 0; hs < HS; ++hs) acc += vpart[(size_t)hs * cB * cD + idx];
    v[idx] = acc;
    if (blockIdx.x == 0 && threadIdx.x < cB) {
        float a = 0.f;
        for (int hs = 0; hs < HS; ++hs) a += cpart[hs * cB + threadIdx.x];
        cvec[threadIdx.x] = a;
    }
}

// ---------------------------------------------------------------------------
// k4: scores[b][n] = (x[b,n]·v[b] + c[b]) * (1/(N*sqrt(H)))
// 16 rows per block; wave w does rows row0+4w..+3 with v held in registers.
__global__ __launch_bounds__(256) void k4_scores(const float* __restrict__ x,
                                                 const float* __restrict__ v,
                                                 const float* __restrict__ cvec,
                                                 float* __restrict__ out) {
    int row0 = blockIdx.x * 16;
    int b = row0 / cN;
    __shared__ float4 vs[cD / 4];
    int t = threadIdx.x;
    vs[t] = ((const float4*)(v + (size_t)b * cD))[t];
    __syncthreads();
    int w = t >> 6, l = t & 63;
    float4 vv[4];
#pragma unroll
    for (int j = 0; j < 4; ++j) vv[j] = vs[l + 64 * j];
    float cb = cvec[b];
    const float scale = (1.0f / 4096.0f) * (1.0f / sqrtf(1792.0f));
    int row = row0 + w * 4;
#pragma unroll
    for (int r = 0; r < 4; ++r) {
        const float4* xp = (const float4*)(x + (size_t)(row + r) * cD);
        float acc = 0.f;
#pragma unroll
        for (int j = 0; j < 4; ++j) acc += dot4(xp[l + 64 * j], vv[j]);
#pragma unroll
        for (int off = 32; off; off >>= 1) acc += __shfl_xor(acc, off);
        if (l == 0) out[row + r] = (acc + cb) * scale;
    }
}

// ---------------------------------------------------------------------------
extern "C" void kernel_launch(void* const* d_in, const int* in_sizes, int n_in,
                              void* d_out, int out_size, void* d_ws, size_t ws_size,
                              hipStream_t stream) {
    const float* x  = (const float*)d_in[0];
    const float* Wq = (const float*)d_in[1];
    const float* bq = (const float*)d_in[2];
    const float* Wk = (const float*)d_in[3];
    const float* bk = (const float*)d_in[4];
    float* out = (float*)d_out;
    float* ws  = (float*)d_ws;

    float* xsum  = ws + OFF_XSUM;
    float* v     = ws + OFF_V;
    float* cvec  = ws + OFF_C;
    float* cpart = ws + OFF_CPART;
    float* vpart = ws + OFF_VPART;
    float* part  = ws + OFF_PART;

    const bool det = ws_size >= TOTAL_DET_FLOATS * sizeof(float);

    if (det) {
        // 1) xsum = sum_n x  (reads x once: 128 MiB)
        k1a_partial<<<cB * NSPLIT, 256, 0, stream>>>(x, part);
        k1b_reduce<<<(cB * cD) / 256, 256, 0, stream>>>(part, xsum);
        // 2+3) fused: ksum in-register -> vpart/cpart  (reads Wk+Wq once: 14.6 MiB)
        k23_fused<<<HS, 512, 0, stream>>>(xsum, Wk, bk, Wq, bq, vpart, cpart);
        kred<<<(cB * cD) / 256, 256, 0, stream>>>(vpart, cpart, v, cvec);
    } else {
        hipMemsetAsync(d_ws, 0, SMALL_FLOATS * sizeof(float), stream);
        k1_atomic<<<cB * NSPLIT, 256, 0, stream>>>(x, xsum);
        k23_atomic<<<HS, 512, 0, stream>>>(xsum, Wk, bk, Wq, bq, v, cvec);
    }

    // 4) scores = (x·v + c) * scale   (reads x again: 128 MiB, mostly L3)
    k4_scores<<<(cB * cN) / 16, 256, 0, stream>>>(x, v, cvec, out);
}